// Round 2
// baseline (176.926 us; speedup 1.0000x reference)
//
#include <hip/hip_runtime.h>

#define NN 4096
#define MM 8192
#define GG 8
#define HH 128
#define NDD 16
#define EE 131072
#define CBLK 64            // cond partial blocks
#define COBJ (MM / CBLK)   // 128 objects per cond block
#define WBLK 8             // W1p gemm blocks (2 rows each)
#define SBLK 128           // scatter blocks
#define CAP 96             // padded CSR row capacity (Poisson(32): P(deg>96) ~ 1e-20)

typedef float nt_f4 __attribute__((ext_vector_type(4)));

// ============ K0: zero the degree counters (16 KB) ============
__global__ __launch_bounds__(1024) void k_zero(int* __restrict__ cnt) {
    ((int4*)cnt)[threadIdx.x] = make_int4(0, 0, 0, 0);  // 1024 * int4 = 4096
}

// ============ K1 front: cond partials (0..63) | W1p (64..71) | padded scatter (72..199) ============
__global__ __launch_bounds__(256) void k_front(
    const float* __restrict__ obj_x, const float* __restrict__ obj_pos,
    const int* __restrict__ nuc, const int* __restrict__ central,
    const int* __restrict__ backbone, const int* __restrict__ obj_batch,
    const int* __restrict__ e_src, const int* __restrict__ e_dst,
    int* __restrict__ cnt, int* __restrict__ col_idx,
    float* __restrict__ partial, float* __restrict__ pcnt,
    const float* __restrict__ Wn, const float* __restrict__ Wc1,
    float* __restrict__ W1p) {
    int b = blockIdx.x, t = threadIdx.x;
    if (b < CBLK) {
        // cond: pool 16-dim inputs. d = t&15, oi = t>>4 (16 objs parallel, 8 passes)
        __shared__ float ls[GG * NDD];
        __shared__ float lc[GG];
        if (t < GG * NDD) ls[t] = 0.f;
        if (t < GG) lc[t] = 0.f;
        __syncthreads();
        int d = t & 15, oi = t >> 4;
        int base = b * COBJ;
#pragma unroll
        for (int pass = 0; pass < COBJ / 16; pass++) {
            int o = base + pass * 16 + oi;
            int nv = nuc[o];
            bool isb = (backbone[o] == 0);
            bool cond = (nv == 0) || ((central[o] != 0) && isb) || ((nv == 2) && isb);
            if (cond) {
                float v = (d < 13) ? obj_x[o * 13 + d] : obj_pos[o * 3 + (d - 13)];
                int g = obj_batch[o];
                atomicAdd(&ls[g * NDD + d], v);
                if (d == 0) atomicAdd(&lc[g], 1.f);
            }
        }
        __syncthreads();
        if (t < GG * NDD) partial[b * (GG * NDD) + t] = ls[t];
        if (t < GG) pcnt[b * GG + t] = lc[t];
        return;
    }
    if (b < CBLK + WBLK) {
        // W1'[a][j] = sum_k Wn[a][k] * Wc1[k][j] -- 8 blocks, 2 rows each
        int wb = b - CBLK;
        int j = t & 127, a0 = t >> 7;
        int a = wb * 2 + a0;
        float acc = 0.f;
        for (int k = 0; k < HH; k++) acc += Wn[a * HH + k] * Wc1[k * HH + j];
        W1p[a * HH + j] = acc;
        return;
    }
    // padded-CSR scatter: slot = atomicAdd(cnt[dst]); col_idx[dst*CAP+slot] = src
    int sb = b - (CBLK + WBLK);
    int i4 = sb * 256 + t;  // 128 blocks * 256 = 32768 int4 = 131072 edges
    int4 d4 = ((const int4*)e_dst)[i4];
    int4 s4 = ((const int4*)e_src)[i4];
    int p;
    p = atomicAdd(&cnt[d4.x], 1); if (p < CAP) col_idx[d4.x * CAP + p] = s4.x;
    p = atomicAdd(&cnt[d4.y], 1); if (p < CAP) col_idx[d4.y * CAP + p] = s4.y;
    p = atomicAdd(&cnt[d4.z], 1); if (p < CAP) col_idx[d4.z * CAP + p] = s4.z;
    p = atomicAdd(&cnt[d4.w], 1); if (p < CAP) col_idx[d4.w * CAP + p] = s4.w;
}

// ============ K2: per-block redundant c1 + xw1 + fused fixup. 128 blocks x 1024. ============
// Each block: computes c1[8][128] from scratch (weights L2-hot), then its 32 rows of
// xw = (x @ W1p + c1[bm[row]]) * rsqrt(deg+1)  -- fully fixed, K4 gathers directly.
__global__ __launch_bounds__(1024) void k_mid(
    const int* __restrict__ timestep, const float* __restrict__ partial,
    const float* __restrict__ pcnt, const float* __restrict__ Wn,
    const float* __restrict__ bn, const float* __restrict__ Wt,
    const float* __restrict__ bt, const float* __restrict__ Wc,
    const float* __restrict__ bc, const float* __restrict__ Wc1,
    const float* __restrict__ x, const float* __restrict__ W1p,
    const int* __restrict__ bm, const int* __restrict__ cnt,
    float* __restrict__ xw) {
    int b = blockIdx.x, t = threadIdx.x;
    int g = t >> 7, j = t & 127;  // (g, j) covers 8 x 128 = 1024
    __shared__ float s16[GG * NDD];
    __shared__ float cinv[GG];
    __shared__ float te[GG * HH];
    __shared__ float pool[GG * HH];
    __shared__ float v2[GG * HH];
    __shared__ float c1s[GG * HH];
    __shared__ float xt[32 * NDD];
    // ---- phase 1: te (all), partial sums (t<128), counts (t<136), x tile (t>=512) ----
    {
        float tv = (float)timestep[g];
        float val;
        if (j < 64) {
            float f = expf(-logf(10000.f) * (float)j / 64.f);
            val = cosf(tv * f);
        } else {
            float f = expf(-logf(10000.f) * (float)(j - 64) / 64.f);
            val = sinf(tv * f);
        }
        te[t] = val;
    }
    if (t < GG * NDD) {
        float s = 0.f;
        for (int q = 0; q < CBLK; q++) s += partial[q * (GG * NDD) + t];
        s16[t] = s;
    } else if (t < GG * NDD + GG) {
        int gg = t - GG * NDD;
        float c = 0.f;
        for (int q = 0; q < CBLK; q++) c += pcnt[q * GG + gg];
        cinv[gg] = 1.f / fmaxf(c, 1.f);
    }
    if (t >= 512) xt[t - 512] = x[b * 32 * NDD + (t - 512)];
    __syncthreads();
    // ---- phase 2: pool[g][j] = bn[j] + mean(cond) @ Wn ----
    {
        float p = bn[j];
        float ci = cinv[g];
#pragma unroll
        for (int d = 0; d < NDD; d++) p += s16[g * NDD + d] * ci * Wn[d * HH + j];
        pool[t] = p;
    }
    __syncthreads();
    // ---- phase 3: v2 = bt + bc + bn + te@Wt + pool@Wc ----
    {
        float acc = bt[j] + bc[j] + bn[j];
#pragma unroll 4
        for (int k = 0; k < HH; k++)
            acc += te[g * HH + k] * Wt[k * HH + j] + pool[g * HH + k] * Wc[k * HH + j];
        v2[t] = acc;
    }
    __syncthreads();
    // ---- phase 4: c1 = v2 @ Wc1 ----
    {
        float cc = 0.f;
#pragma unroll 4
        for (int k = 0; k < HH; k++) cc += v2[g * HH + k] * Wc1[k * HH + j];
        c1s[t] = cc;
    }
    __syncthreads();
    // ---- phase 5: xw1 (32 rows) + fixup ----
    {
        int col = j, rh = g;  // rh 0..7, 4 rows each
        int r0 = b * 32;
        float acc[4] = {0.f, 0.f, 0.f, 0.f};
#pragma unroll
        for (int k = 0; k < NDD; k++) {
            float wv = W1p[k * HH + col];
#pragma unroll
            for (int i = 0; i < 4; i++) acc[i] += xt[(rh * 4 + i) * NDD + k] * wv;
        }
#pragma unroll
        for (int i = 0; i < 4; i++) {
            int row = r0 + rh * 4 + i;
            int gr = bm[row];
            float dd = rsqrtf((float)cnt[row] + 1.f);  // +1: self loop
            xw[row * HH + col] = (acc[i] + c1s[gr * HH + col]) * dd;
        }
    }
}

// ============ K4: conv1 aggregate + fused gemm2 (Wc2 staged in LDS). One wave per dst. ============
__global__ __launch_bounds__(256) void k_conv1(
    const float* __restrict__ xw, const int* __restrict__ cnt,
    const int* __restrict__ col_idx, const float* __restrict__ b1,
    const float* __restrict__ Wc2, float* __restrict__ xw2) {
    int w = threadIdx.x >> 6, l = threadIdx.x & 63;
    int dst = blockIdx.x * 4 + w;
    int deg = cnt[dst];
    float dd = rsqrtf((float)deg + 1.f);
    int end = deg < CAP ? deg : CAP;
    const float2* xwp = (const float2*)xw;
    float2 acc = xwp[dst * 64 + l];  // self loop, pre-scaled & fixed
    const int* ci = col_idx + dst * CAP;
    int e = 0;
    for (; e + 7 < end; e += 8) {
        int s0 = ci[e], s1 = ci[e + 1], s2 = ci[e + 2], s3 = ci[e + 3];
        int s4 = ci[e + 4], s5 = ci[e + 5], s6 = ci[e + 6], s7 = ci[e + 7];
        float2 v0 = xwp[s0 * 64 + l], v1 = xwp[s1 * 64 + l];
        float2 v2 = xwp[s2 * 64 + l], v3 = xwp[s3 * 64 + l];
        float2 v4 = xwp[s4 * 64 + l], v5 = xwp[s5 * 64 + l];
        float2 v6 = xwp[s6 * 64 + l], v7 = xwp[s7 * 64 + l];
        acc.x += ((v0.x + v1.x) + (v2.x + v3.x)) + ((v4.x + v5.x) + (v6.x + v7.x));
        acc.y += ((v0.y + v1.y) + (v2.y + v3.y)) + ((v4.y + v5.y) + (v6.y + v7.y));
    }
    for (; e + 3 < end; e += 4) {
        int s0 = ci[e], s1 = ci[e + 1], s2 = ci[e + 2], s3 = ci[e + 3];
        float2 v0 = xwp[s0 * 64 + l], v1 = xwp[s1 * 64 + l];
        float2 v2 = xwp[s2 * 64 + l], v3 = xwp[s3 * 64 + l];
        acc.x += (v0.x + v1.x) + (v2.x + v3.x);
        acc.y += (v0.y + v1.y) + (v2.y + v3.y);
    }
    for (; e < end; e++) {
        float2 v = xwp[ci[e] * 64 + l];
        acc.x += v.x;
        acc.y += v.y;
    }
    float2 h;
    h.x = fmaxf(dd * acc.x + b1[2 * l], 0.f);
    h.y = fmaxf(dd * acc.y + b1[2 * l + 1], 0.f);
    __shared__ float hr[4][HH];
    __shared__ float wsm[64 * HH];  // 32 KB: half of Wc2 at a time
    *(float2*)&hr[w][2 * l] = h;
    float2 o = {0.f, 0.f};
#pragma unroll
    for (int half = 0; half < 2; half++) {
        __syncthreads();  // hr ready (half 0) / previous half's reads done (half 1)
        const float4* src4 = (const float4*)(Wc2 + half * 64 * HH);
        float4* dst4 = (float4*)wsm;
#pragma unroll
        for (int i = 0; i < (64 * HH / 4) / 256; i++)
            dst4[i * 256 + threadIdx.x] = src4[i * 256 + threadIdx.x];
        __syncthreads();
#pragma unroll 4
        for (int k = 0; k < 64; k++) {
            float hk = hr[w][half * 64 + k];
            float2 wv = *(const float2*)&wsm[k * HH + 2 * l];
            o.x += hk * wv.x;
            o.y += hk * wv.y;
        }
    }
    o.x *= dd;
    o.y *= dd;
    ((float2*)xw2)[dst * 64 + l] = o;
}

// ============ K5: conv2 aggregate + pred + sl/sr. One wave per dst row. ============
__global__ __launch_bounds__(256) void k_conv2_head(
    const float* __restrict__ xw, const int* __restrict__ cnt,
    const int* __restrict__ col_idx, const float* __restrict__ b2,
    const float* __restrict__ Wo, const float* __restrict__ bo,
    const float* __restrict__ we, float* __restrict__ out_pred,
    float* __restrict__ sl, float* __restrict__ sr) {
    int w = threadIdx.x >> 6, l = threadIdx.x & 63;
    int dst = blockIdx.x * 4 + w;
    int deg = cnt[dst];
    float dd = rsqrtf((float)deg + 1.f);
    int end = deg < CAP ? deg : CAP;
    const float2* xwp = (const float2*)xw;
    float2 acc = xwp[dst * 64 + l];
    const int* ci = col_idx + dst * CAP;
    int e = 0;
    for (; e + 7 < end; e += 8) {
        int s0 = ci[e], s1 = ci[e + 1], s2 = ci[e + 2], s3 = ci[e + 3];
        int s4 = ci[e + 4], s5 = ci[e + 5], s6 = ci[e + 6], s7 = ci[e + 7];
        float2 v0 = xwp[s0 * 64 + l], v1 = xwp[s1 * 64 + l];
        float2 v2 = xwp[s2 * 64 + l], v3 = xwp[s3 * 64 + l];
        float2 v4 = xwp[s4 * 64 + l], v5 = xwp[s5 * 64 + l];
        float2 v6 = xwp[s6 * 64 + l], v7 = xwp[s7 * 64 + l];
        acc.x += ((v0.x + v1.x) + (v2.x + v3.x)) + ((v4.x + v5.x) + (v6.x + v7.x));
        acc.y += ((v0.y + v1.y) + (v2.y + v3.y)) + ((v4.y + v5.y) + (v6.y + v7.y));
    }
    for (; e + 3 < end; e += 4) {
        int s0 = ci[e], s1 = ci[e + 1], s2 = ci[e + 2], s3 = ci[e + 3];
        float2 v0 = xwp[s0 * 64 + l], v1 = xwp[s1 * 64 + l];
        float2 v2 = xwp[s2 * 64 + l], v3 = xwp[s3 * 64 + l];
        acc.x += (v0.x + v1.x) + (v2.x + v3.x);
        acc.y += (v0.y + v1.y) + (v2.y + v3.y);
    }
    for (; e < end; e++) {
        float2 v = xwp[ci[e] * 64 + l];
        acc.x += v.x;
        acc.y += v.y;
    }
    float2 h;
    h.x = fmaxf(dd * acc.x + b2[2 * l], 0.f);
    h.y = fmaxf(dd * acc.y + b2[2 * l + 1], 0.f);
    __shared__ float hr[4][HH];
    *(float2*)&hr[w][2 * l] = h;
    __syncthreads();
    // pred: c = l&15, partial p = l>>4 over k in [32p, 32p+32)
    {
        int c = l & 15, p = l >> 4;
        float a = 0.f;
#pragma unroll 4
        for (int k = p * 32; k < p * 32 + 32; k++) a += hr[w][k] * Wo[k * NDD + c];
        a += __shfl_xor(a, 16);
        a += __shfl_xor(a, 32);
        if (p == 0) out_pred[dst * NDD + c] = a + bo[c];
    }
    // sl/sr
    {
        float h0 = hr[w][l], h1v = hr[w][64 + l];
        float pl = h0 * we[l] + h1v * we[64 + l];
        float pr = h0 * we[HH + l] + h1v * we[HH + 64 + l];
        for (int off = 32; off; off >>= 1) {
            pl += __shfl_down(pl, off);
            pr += __shfl_down(pr, off);
        }
        if (l == 0) {
            sl[dst] = pl;
            sr[dst] = pr;
        }
    }
}

// ============ K6: edge logits, nontemporal stores, rows b and NN-2-b per block ============
__global__ __launch_bounds__(256) void k_edges(const float* __restrict__ sl,
                                               const float* __restrict__ sr,
                                               const float* __restrict__ be_p,
                                               float* __restrict__ out) {
    int b = blockIdx.x, t = threadIdx.x;
    float be = be_p[0];
#pragma unroll
    for (int half = 0; half < 2; half++) {
        int r = half == 0 ? b : (NN - 2 - b);
        int off = r * (2 * NN - r - 1) / 2;  // < 2^23, fits int
        int len = NN - 1 - r;
        float s = sl[r] + be;
        const float* sp = sr + r + 1;
        float* op = out + off;
        int hd = (4 - (off & 3)) & 3;
        if (hd > len) hd = len;
        if (t < hd) __builtin_nontemporal_store(s + sp[t], op + t);
        int body = (len - hd) >> 2;
        float* opb = op + hd;
        const float* spb = sp + hd;
        for (int i = t; i < body; i += 256) {
            int base = 4 * i;
            nt_f4 v;
            v.x = s + spb[base];
            v.y = s + spb[base + 1];
            v.z = s + spb[base + 2];
            v.w = s + spb[base + 3];
            __builtin_nontemporal_store(v, (nt_f4*)(opb + base));
        }
        int tail = hd + body * 4;
        int rem = len - tail;
        if (t < rem) __builtin_nontemporal_store(s + sp[tail + t], op + tail + t);
    }
}

extern "C" void kernel_launch(void* const* d_in, const int* in_sizes, int n_in,
                              void* d_out, int out_size, void* d_ws, size_t ws_size,
                              hipStream_t stream) {
    const float* x = (const float*)d_in[0];
    const int* e_src = (const int*)d_in[1];
    const int* e_dst = e_src + EE;
    const int* timestep = (const int*)d_in[2];
    const int* batch_map = (const int*)d_in[3];
    const int* nuc = (const int*)d_in[4];
    const int* central = (const int*)d_in[5];
    const int* backbone = (const int*)d_in[6];
    const float* obj_x = (const float*)d_in[7];
    const float* obj_pos = (const float*)d_in[8];
    const int* obj_batch = (const int*)d_in[9];
    const float* W_node = (const float*)d_in[10];
    const float* b_node = (const float*)d_in[11];
    const float* W_cond = (const float*)d_in[12];
    const float* b_cond = (const float*)d_in[13];
    const float* W_time = (const float*)d_in[14];
    const float* b_time = (const float*)d_in[15];
    const float* W_conv1 = (const float*)d_in[16];
    const float* b_conv1 = (const float*)d_in[17];
    const float* W_conv2 = (const float*)d_in[18];
    const float* b_conv2 = (const float*)d_in[19];
    const float* W_out = (const float*)d_in[20];
    const float* b_out = (const float*)d_in[21];
    const float* w_edge = (const float*)d_in[22];
    const float* b_edge = (const float*)d_in[23];

    // workspace
    float* ws = (float*)d_ws;
    float* bufA = ws;                        // N*H (xw1', fixed)
    float* bufB = bufA + NN * HH;            // N*H (xw2')
    float* W1p = bufB + NN * HH;             // 16*H
    float* partial = W1p + NDD * HH;         // CBLK*G*16
    float* pcnt = partial + CBLK * GG * NDD; // CBLK*G
    float* sl = pcnt + CBLK * GG;            // N
    float* sr = sl + NN;                     // N
    int* cnt = (int*)(sr + NN);              // N (degree counters)
    int* col_idx = cnt + NN;                 // N*CAP padded CSR

    float* out_pred = (float*)d_out;
    float* out_edges = out_pred + NN * NDD;

    // K0: zero degree counters
    k_zero<<<1, 1024, 0, stream>>>(cnt);
    // K1: cond partials + W1p + padded-CSR scatter
    k_front<<<CBLK + WBLK + SBLK, 256, 0, stream>>>(obj_x, obj_pos, nuc, central,
                                                    backbone, obj_batch, e_src, e_dst,
                                                    cnt, col_idx, partial, pcnt,
                                                    W_node, W_conv1, W1p);
    // K2: redundant-c1 + xw1 + fixup (fully fixed xw1')
    k_mid<<<NN / 32, 1024, 0, stream>>>(timestep, partial, pcnt, W_node, b_node,
                                        W_time, b_time, W_cond, b_cond, W_conv1,
                                        x, W1p, batch_map, cnt, bufA);
    // K4: conv1 agg + gemm2 -> xw2'
    k_conv1<<<NN / 4, 256, 0, stream>>>(bufA, cnt, col_idx, b_conv1, W_conv2, bufB);
    // K5: conv2 agg + pred + sl/sr
    k_conv2_head<<<NN / 4, 256, 0, stream>>>(bufB, cnt, col_idx, b_conv2, W_out,
                                             b_out, w_edge, out_pred, sl, sr);
    // K6: edge logits
    k_edges<<<NN / 2, 256, 0, stream>>>(sl, sr, b_edge, out_edges);
}